// Round 1
// baseline (2468.410 us; speedup 1.0000x reference)
//
#include <hip/hip_runtime.h>

#define Cn 16
#define Dn 96
#define Sn (Dn*Dn*Dn)        /* 884736 */
#define DSTRIDE (Dn*Dn)      /* 9216 */
#define ENC_NEG_INF 0x007FFFFFu

// monotonic float<->uint map for atomicMax on signed floats
__device__ __forceinline__ unsigned encf(float f){
    unsigned u = __float_as_uint(f);
    return (u & 0x80000000u) ? ~u : (u | 0x80000000u);
}
__device__ __forceinline__ float decf(unsigned u){
    return (u & 0x80000000u) ? __uint_as_float(u ^ 0x80000000u) : __uint_as_float(~u);
}
// exact identity tanh(x) = 1 - 2/(exp(2x)+1); v_exp_f32 + v_rcp, ~1e-7 rel err
__device__ __forceinline__ float ftanh(float x){
    float t = __expf(2.0f*x);
    return 1.0f - __fdividef(2.0f, t + 1.0f);
}

__global__ void init_kernel(unsigned* __restrict__ maxv){
    if (threadIdx.x < 10) maxv[threadIdx.x] = ENC_NEG_INF;
}

// maskA := 1.0, and global max of x ch3 -> slot (pre-max for step 0)
__global__ __launch_bounds__(256) void prep_kernel(const float* __restrict__ x3,
    float* __restrict__ maskA, unsigned* __restrict__ slot)
{
    const int idx = blockIdx.x*256 + threadIdx.x;
    maskA[idx] = 1.0f;
    float v = x3[idx];
    #pragma unroll
    for (int o=32;o;o>>=1) v = fmaxf(v, __shfl_down(v, o));
    __shared__ float red[4];
    const int lane = threadIdx.x & 63, wid = threadIdx.x >> 6;
    if (lane==0) red[wid]=v;
    __syncthreads();
    if (threadIdx.x==0){
        float m = fmaxf(fmaxf(red[0],red[1]), fmaxf(red[2],red[3]));
        atomicMax(slot, encf(m));
    }
}

// fused: masked-read x_in, dwconv(3x3x3, groups=16, 48ch) -> tanh MLP 48->64->64->16
// -> residual add -> write unmasked x_new; atomicMax of new ch3 -> slot_post
__global__ __launch_bounds__(64) void update_kernel(
    const float* __restrict__ xin, const float* __restrict__ min_,
    float* __restrict__ xout,
    const float* __restrict__ wp, const float* __restrict__ bp,
    const float* __restrict__ w1, const float* __restrict__ b1,
    const float* __restrict__ w2, const float* __restrict__ b2,
    const float* __restrict__ w3, const float* __restrict__ b3,
    unsigned* __restrict__ slot_post)
{
    __shared__ float h1s[64*65];   // stride 65: conflict-free b32 read/write
    const int tid = threadIdx.x;
    const int idx = blockIdx.x*64 + tid;
    const int w = idx % Dn;
    const int h = (idx / Dn) % Dn;
    const int d = idx / DSTRIDE;

    float p[48];
    #pragma unroll
    for (int j=0;j<48;j++) p[j] = bp[j];

    // depthwise 3x3x3 grouped conv (zero pad SAME), input pre-masked by min_
    #pragma unroll 1
    for (int t=0; t<27; ++t) {
        const int dz = t/9 - 1;
        const int dy = (t/3)%3 - 1;
        const int dx = t%3 - 1;
        const int zz = d+dz, yy = h+dy, xx = w+dx;
        if ((unsigned)zz < (unsigned)Dn && (unsigned)yy < (unsigned)Dn &&
            (unsigned)xx < (unsigned)Dn) {
            const int noff = idx + dz*DSTRIDE + dy*Dn + dx;
            const float m = min_[noff];
            #pragma unroll
            for (int c=0;c<Cn;c++){
                const float xv = xin[(size_t)c*Sn + noff] * m;
                p[3*c+0] = fmaf(xv, wp[(3*c+0)*27 + t], p[3*c+0]);
                p[3*c+1] = fmaf(xv, wp[(3*c+1)*27 + t], p[3*c+1]);
                p[3*c+2] = fmaf(xv, wp[(3*c+2)*27 + t], p[3*c+2]);
            }
        }
    }

    // pw1: 48 -> 64, tanh; j rolled (uniform -> s_load weights), k unrolled (p in VGPRs);
    // dynamic-index h1 write goes to LDS to avoid scratch / full-unroll code bloat
    #pragma unroll 1
    for (int j=0;j<64;++j){
        float a = b1[j];
        #pragma unroll
        for (int k=0;k<48;++k) a = fmaf(w1[j*48+k], p[k], a);
        h1s[tid*65 + j] = ftanh(a);
    }

    float h1r[64];
    #pragma unroll
    for (int k=0;k<64;++k) h1r[k] = h1s[tid*65+k];

    float oacc[16];
    #pragma unroll
    for (int c=0;c<16;++c) oacc[c] = b3[c];

    // pw2 (64->64, tanh) fused with pw3 (64->16): h2 never materialized
    #pragma unroll 1
    for (int j=0;j<64;++j){
        float a = b2[j];
        #pragma unroll
        for (int k=0;k<64;++k) a = fmaf(w2[j*64+k], h1r[k], a);
        const float h2 = ftanh(a);
        #pragma unroll
        for (int c=0;c<16;++c) oacc[c] = fmaf(w3[c*64+j], h2, oacc[c]);
    }

    // residual: x_new = masked x_in + out; track ch3 for global max
    const float mcen = min_[idx];
    float v3 = 0.0f;
    #pragma unroll
    for (int c=0;c<Cn;++c){
        const float xn = fmaf(xin[(size_t)c*Sn+idx], mcen, oacc[c]);
        xout[(size_t)c*Sn+idx] = xn;
        if (c==3) v3 = xn;
    }

    #pragma unroll
    for (int o=32;o;o>>=1) v3 = fmaxf(v3, __shfl_down(v3, o));
    if (tid==0) atomicMax(slot_post, encf(v3));
}

// alive0 from masked old ch3, alive1 from unmasked new ch3; life mask includes
// the boundary zero x[:, :, -1, 48:, :]=0; also produces next step's pre-max
__global__ __launch_bounds__(256) void mask_kernel(
    const float* __restrict__ xin3, const float* __restrict__ min_,
    const float* __restrict__ xout3, float* __restrict__ mout,
    const unsigned* __restrict__ slot_pre, const unsigned* __restrict__ slot_post,
    unsigned* __restrict__ slot_next)
{
    const int idx = blockIdx.x*256 + threadIdx.x;
    const int w = idx % Dn;
    const int h = (idx / Dn) % Dn;
    const int d = idx / DSTRIDE;
    const float th0 = 0.1f * decf(*slot_pre);
    const float th1 = 0.1f * decf(*slot_post);
    float a0 = -INFINITY, a1 = -INFINITY;
    #pragma unroll
    for (int t=0;t<27;++t){
        const int dz=t/9-1, dy=(t/3)%3-1, dx=t%3-1;
        const int zz=d+dz, yy=h+dy, xx=w+dx;
        if ((unsigned)zz<(unsigned)Dn && (unsigned)yy<(unsigned)Dn &&
            (unsigned)xx<(unsigned)Dn){
            const int noff = idx + dz*DSTRIDE + dy*Dn + dx;
            a0 = fmaxf(a0, xin3[noff]*min_[noff]);
            a1 = fmaxf(a1, xout3[noff]);
        }
    }
    const bool life = (a0 > th0) && (a1 > th1) && !(d==Dn-1 && h>=48);
    const float mv = life ? 1.0f : 0.0f;
    mout[idx] = mv;

    float f3 = xout3[idx]*mv;   // final ch3 value -> pre-max of next step
    #pragma unroll
    for (int o=32;o;o>>=1) f3 = fmaxf(f3, __shfl_down(f3, o));
    __shared__ float red[4];
    const int lane = threadIdx.x & 63, wid = threadIdx.x >> 6;
    if (lane==0) red[wid]=f3;
    __syncthreads();
    if (threadIdx.x==0){
        float m = fmaxf(fmaxf(red[0],red[1]), fmaxf(red[2],red[3]));
        atomicMax(slot_next, encf(m));
    }
}

// final: apply last step's mask in place on d_out
__global__ __launch_bounds__(256) void apply_kernel(float* __restrict__ x,
    const float* __restrict__ mk)
{
    const int idx = blockIdx.x*256 + threadIdx.x;
    const float m = mk[idx];
    #pragma unroll
    for (int c=0;c<Cn;++c) x[(size_t)c*Sn+idx] *= m;
}

extern "C" void kernel_launch(void* const* d_in, const int* in_sizes, int n_in,
                              void* d_out, int out_size, void* d_ws, size_t ws_size,
                              hipStream_t stream)
{
    const float* x0 = (const float*)d_in[0];
    const float* wp = (const float*)d_in[1];
    const float* bp = (const float*)d_in[2];
    const float* w1 = (const float*)d_in[3];
    const float* b1 = (const float*)d_in[4];
    const float* w2 = (const float*)d_in[5];
    const float* b2 = (const float*)d_in[6];
    const float* w3 = (const float*)d_in[7];
    const float* b3 = (const float*)d_in[8];
    float* out = (float*)d_out;

    // ws layout: xbuf (16*Sn f32) | maskA (Sn) | maskB (Sn) | maxv (10 u32)  ~64 MB
    float* xbuf  = (float*)d_ws;
    float* maskA = xbuf + (size_t)Cn*Sn;
    float* maskB = maskA + Sn;
    unsigned* maxv = (unsigned*)(maskB + Sn);

    init_kernel<<<1, 64, 0, stream>>>(maxv);
    prep_kernel<<<Sn/256, 256, 0, stream>>>(x0 + (size_t)3*Sn, maskA, &maxv[0]);

    // ping-pong unmasked x_new between ws buffer and d_out; masks alternate A/B
    const float* xi[4] = {x0,   xbuf, out,  xbuf};
    float*       xo[4] = {xbuf, out,  xbuf, out};
    const float* mi[4] = {maskA, maskB, maskA, maskB};
    float*       mo[4] = {maskB, maskA, maskB, maskA};

    for (int s=0; s<4; ++s){
        update_kernel<<<Sn/64, 64, 0, stream>>>(xi[s], mi[s], xo[s],
            wp, bp, w1, b1, w2, b2, w3, b3, &maxv[2*s+1]);
        mask_kernel<<<Sn/256, 256, 0, stream>>>(xi[s]+(size_t)3*Sn, mi[s],
            xo[s]+(size_t)3*Sn, mo[s], &maxv[2*s], &maxv[2*s+1], &maxv[2*s+2]);
    }
    apply_kernel<<<Sn/256, 256, 0, stream>>>(out, maskA);
}

// Round 2
// 2329.789 us; speedup vs baseline: 1.0595x; 1.0595x over previous
//
#include <hip/hip_runtime.h>

#define Cn 16
#define Dn 96
#define Sn (Dn*Dn*Dn)        /* 884736 */
#define DSTRIDE (Dn*Dn)      /* 9216 */
#define ENC_NEG_INF 0x007FFFFFu

// monotonic float<->uint map for atomicMax on signed floats
__device__ __forceinline__ unsigned encf(float f){
    unsigned u = __float_as_uint(f);
    return (u & 0x80000000u) ? ~u : (u | 0x80000000u);
}
__device__ __forceinline__ float decf(unsigned u){
    return (u & 0x80000000u) ? __uint_as_float(u ^ 0x80000000u) : __uint_as_float(~u);
}
// exact identity tanh(x) = 1 - 2/(exp(2x)+1); v_exp_f32 + fast divide, ~1e-7 rel err
__device__ __forceinline__ float ftanh(float x){
    float t = __expf(2.0f*x);
    return 1.0f - __fdividef(2.0f, t + 1.0f);
}

__global__ void init_kernel(unsigned* __restrict__ maxv){
    if (threadIdx.x < 10) maxv[threadIdx.x] = ENC_NEG_INF;
}

// transpose w2 (64x64 -> w2T[k][j]) and w3 (16x64 -> w3T[j][c]); 16 blocks x 256
__global__ void tr_kernel(const float* __restrict__ w2, const float* __restrict__ w3,
                          float* __restrict__ w2T, float* __restrict__ w3T){
    const int i = blockIdx.x*256 + threadIdx.x;
    if (i < 4096){ const int j = i>>6, k = i&63; w2T[k*64+j] = w2[i]; }
    if (i < 1024){ const int c = i>>6, j = i&63; w3T[j*16+c] = w3[i]; }
}

// maskA := 1.0, and global max of x ch3 -> slot (pre-max for step 0)
__global__ __launch_bounds__(256) void prep_kernel(const float* __restrict__ x3,
    float* __restrict__ maskA, unsigned* __restrict__ slot)
{
    const int idx = blockIdx.x*256 + threadIdx.x;
    maskA[idx] = 1.0f;
    float v = x3[idx];
    #pragma unroll
    for (int o=32;o;o>>=1) v = fmaxf(v, __shfl_down(v, o));
    __shared__ float red[4];
    const int lane = threadIdx.x & 63, wid = threadIdx.x >> 6;
    if (lane==0) red[wid]=v;
    __syncthreads();
    if (threadIdx.x==0){
        float m = fmaxf(fmaxf(red[0],red[1]), fmaxf(red[2],red[3]));
        atomicMax(slot, encf(m));
    }
}

// fused: masked-read x_in, dwconv(3x3x3, groups=16, 48ch) -> MLP 48->64->64->16
// restructured k-outer pw2: h1 never materialized (no LDS, no h1 array).
// Arithmetic order bit-identical to the j-outer version.
__global__ __launch_bounds__(64, 3) void update_kernel(
    const float* __restrict__ xin, const float* __restrict__ min_,
    float* __restrict__ xout,
    const float* __restrict__ wp, const float* __restrict__ bp,
    const float* __restrict__ w1, const float* __restrict__ b1,
    const float* __restrict__ w2T, const float* __restrict__ b2,
    const float* __restrict__ w3T, const float* __restrict__ b3,
    unsigned* __restrict__ slot_post)
{
    const int tid = threadIdx.x;
    const int idx = blockIdx.x*64 + tid;
    const int w = idx % Dn;
    const int h = (idx / Dn) % Dn;
    const int d = idx / DSTRIDE;

    float p[48];
    #pragma unroll
    for (int j=0;j<48;j++) p[j] = bp[j];

    // depthwise 3x3x3 grouped conv (zero pad SAME), input masked by min_
    #pragma unroll 1
    for (int t=0; t<27; ++t) {
        const int dz = t/9 - 1;
        const int dy = (t/3)%3 - 1;
        const int dx = t%3 - 1;
        const int zz = d+dz, yy = h+dy, xx = w+dx;
        if ((unsigned)zz < (unsigned)Dn && (unsigned)yy < (unsigned)Dn &&
            (unsigned)xx < (unsigned)Dn) {
            const int noff = idx + dz*DSTRIDE + dy*Dn + dx;
            const float m = min_[noff];
            #pragma unroll
            for (int c=0;c<Cn;c++){
                const float xv = xin[(size_t)c*Sn + noff] * m;
                p[3*c+0] = fmaf(xv, wp[(3*c+0)*27 + t], p[3*c+0]);
                p[3*c+1] = fmaf(xv, wp[(3*c+1)*27 + t], p[3*c+1]);
                p[3*c+2] = fmaf(xv, wp[(3*c+2)*27 + t], p[3*c+2]);
            }
        }
    }

    // k-outer fused pw1+pw2: h1k computed on the fly, rank-1 update of acc2.
    // acc2[j] gets contributions in ascending k (same order as j-outer dot).
    float acc2[64];
    #pragma unroll
    for (int j=0;j<64;++j) acc2[j] = b2[j];

    #pragma unroll 1
    for (int k=0;k<64;++k){
        float a = b1[k];
        #pragma unroll
        for (int i=0;i<48;++i) a = fmaf(w1[k*48+i], p[i], a);
        const float h1k = ftanh(a);
        const float* __restrict__ wrow = w2T + k*64;   // uniform addr -> s_load
        #pragma unroll
        for (int j=0;j<64;++j) acc2[j] = fmaf(wrow[j], h1k, acc2[j]);
    }

    float oacc[16];
    #pragma unroll
    for (int c=0;c<16;++c) oacc[c] = b3[c];

    // pw3: fully unrolled (h2 const-indexed); w3T[j][c] contiguous per j
    #pragma unroll
    for (int j=0;j<64;++j){
        const float h2 = ftanh(acc2[j]);
        #pragma unroll
        for (int c=0;c<16;++c) oacc[c] = fmaf(w3T[j*16+c], h2, oacc[c]);
    }

    // residual: x_new = masked x_in + out; track ch3 for global max
    const float mcen = min_[idx];
    float v3 = 0.0f;
    #pragma unroll
    for (int c=0;c<Cn;++c){
        const float xn = fmaf(xin[(size_t)c*Sn+idx], mcen, oacc[c]);
        xout[(size_t)c*Sn+idx] = xn;
        if (c==3) v3 = xn;
    }

    #pragma unroll
    for (int o=32;o;o>>=1) v3 = fmaxf(v3, __shfl_down(v3, o));
    if (tid==0) atomicMax(slot_post, encf(v3));
}

// alive0 from masked old ch3, alive1 from unmasked new ch3; life mask includes
// the boundary zero x[:, :, -1, 48:, :]=0; also produces next step's pre-max
__global__ __launch_bounds__(256) void mask_kernel(
    const float* __restrict__ xin3, const float* __restrict__ min_,
    const float* __restrict__ xout3, float* __restrict__ mout,
    const unsigned* __restrict__ slot_pre, const unsigned* __restrict__ slot_post,
    unsigned* __restrict__ slot_next)
{
    const int idx = blockIdx.x*256 + threadIdx.x;
    const int w = idx % Dn;
    const int h = (idx / Dn) % Dn;
    const int d = idx / DSTRIDE;
    const float th0 = 0.1f * decf(*slot_pre);
    const float th1 = 0.1f * decf(*slot_post);
    float a0 = -INFINITY, a1 = -INFINITY;
    #pragma unroll
    for (int t=0;t<27;++t){
        const int dz=t/9-1, dy=(t/3)%3-1, dx=t%3-1;
        const int zz=d+dz, yy=h+dy, xx=w+dx;
        if ((unsigned)zz<(unsigned)Dn && (unsigned)yy<(unsigned)Dn &&
            (unsigned)xx<(unsigned)Dn){
            const int noff = idx + dz*DSTRIDE + dy*Dn + dx;
            a0 = fmaxf(a0, xin3[noff]*min_[noff]);
            a1 = fmaxf(a1, xout3[noff]);
        }
    }
    const bool life = (a0 > th0) && (a1 > th1) && !(d==Dn-1 && h>=48);
    const float mv = life ? 1.0f : 0.0f;
    mout[idx] = mv;

    float f3 = xout3[idx]*mv;   // final ch3 value -> pre-max of next step
    #pragma unroll
    for (int o=32;o;o>>=1) f3 = fmaxf(f3, __shfl_down(f3, o));
    __shared__ float red[4];
    const int lane = threadIdx.x & 63, wid = threadIdx.x >> 6;
    if (lane==0) red[wid]=f3;
    __syncthreads();
    if (threadIdx.x==0){
        float m = fmaxf(fmaxf(red[0],red[1]), fmaxf(red[2],red[3]));
        atomicMax(slot_next, encf(m));
    }
}

// final: apply last step's mask in place on d_out
__global__ __launch_bounds__(256) void apply_kernel(float* __restrict__ x,
    const float* __restrict__ mk)
{
    const int idx = blockIdx.x*256 + threadIdx.x;
    const float m = mk[idx];
    #pragma unroll
    for (int c=0;c<Cn;++c) x[(size_t)c*Sn+idx] *= m;
}

extern "C" void kernel_launch(void* const* d_in, const int* in_sizes, int n_in,
                              void* d_out, int out_size, void* d_ws, size_t ws_size,
                              hipStream_t stream)
{
    const float* x0 = (const float*)d_in[0];
    const float* wp = (const float*)d_in[1];
    const float* bp = (const float*)d_in[2];
    const float* w1 = (const float*)d_in[3];
    const float* b1 = (const float*)d_in[4];
    const float* w2 = (const float*)d_in[5];
    const float* b2 = (const float*)d_in[6];
    const float* w3 = (const float*)d_in[7];
    const float* b3 = (const float*)d_in[8];
    float* out = (float*)d_out;

    // ws layout: xbuf (16*Sn f32) | maskA (Sn) | maskB (Sn) | maxv (16 u32) |
    //            w2T (4096 f32) | w3T (1024 f32)   ~63.8 MB
    float* xbuf  = (float*)d_ws;
    float* maskA = xbuf + (size_t)Cn*Sn;
    float* maskB = maskA + Sn;
    unsigned* maxv = (unsigned*)(maskB + Sn);
    float* w2T = (float*)(maxv + 16);
    float* w3T = w2T + 4096;

    init_kernel<<<1, 64, 0, stream>>>(maxv);
    tr_kernel<<<16, 256, 0, stream>>>(w2, w3, w2T, w3T);
    prep_kernel<<<Sn/256, 256, 0, stream>>>(x0 + (size_t)3*Sn, maskA, &maxv[0]);

    // ping-pong unmasked x_new between ws buffer and d_out; masks alternate A/B
    const float* xi[4] = {x0,   xbuf, out,  xbuf};
    float*       xo[4] = {xbuf, out,  xbuf, out};
    const float* mi[4] = {maskA, maskB, maskA, maskB};
    float*       mo[4] = {maskB, maskA, maskB, maskA};

    for (int s=0; s<4; ++s){
        update_kernel<<<Sn/64, 64, 0, stream>>>(xi[s], mi[s], xo[s],
            wp, bp, w1, b1, w2T, b2, w3T, b3, &maxv[2*s+1]);
        mask_kernel<<<Sn/256, 256, 0, stream>>>(xi[s]+(size_t)3*Sn, mi[s],
            xo[s]+(size_t)3*Sn, mo[s], &maxv[2*s], &maxv[2*s+1], &maxv[2*s+2]);
    }
    apply_kernel<<<Sn/256, 256, 0, stream>>>(out, maskA);
}

// Round 4
// 2297.424 us; speedup vs baseline: 1.0744x; 1.0141x over previous
//
#include <hip/hip_runtime.h>

#define Cn 16
#define Dn 96
#define Sn (Dn*Dn*Dn)        /* 884736 */
#define DSTRIDE (Dn*Dn)      /* 9216 */
#define ENC_NEG_INF 0x007FFFFFu

typedef float v2f __attribute__((ext_vector_type(2)));

__device__ __forceinline__ v2f ld2(const float* p){
    v2f r; __builtin_memcpy(&r, p, 8); return r;
}
// monotonic float<->uint map for atomicMax on signed floats
__device__ __forceinline__ unsigned encf(float f){
    unsigned u = __float_as_uint(f);
    return (u & 0x80000000u) ? ~u : (u | 0x80000000u);
}
__device__ __forceinline__ float decf(unsigned u){
    return (u & 0x80000000u) ? __uint_as_float(u ^ 0x80000000u) : __uint_as_float(~u);
}
// tanh(x) = 1 - 2/(exp(2x)+1)
__device__ __forceinline__ float ftanh(float x){
    float t = __expf(2.0f*x);
    return 1.0f - __fdividef(2.0f, t + 1.0f);
}
__device__ __forceinline__ int clampi(int v){ return v<0?0:(v>Dn-1?Dn-1:v); }

__global__ void init_kernel(unsigned* __restrict__ maxv){
    if (threadIdx.x < 16) maxv[threadIdx.x] = ENC_NEG_INF;
}

// Reorder weights once:
//  w2T[k*64+j]=w2[j*64+k]; w3T[j*16+c]=w3[c*64+j];
//  w1P[k*48+q*16+c]=w1[k*48+3c+q]; wpT[t*48+q*16+c]=wp[(3c+q)*27+t]; bpP[q*16+c]=bp[3c+q]
__global__ void tr_kernel(const float* __restrict__ w2, const float* __restrict__ w3,
                          const float* __restrict__ w1, const float* __restrict__ wp,
                          const float* __restrict__ bp,
                          float* __restrict__ w2T, float* __restrict__ w3T,
                          float* __restrict__ w1P, float* __restrict__ wpT,
                          float* __restrict__ bpP){
    const int i = blockIdx.x*256 + threadIdx.x;
    if (i < 4096){ w2T[i] = w2[(i&63)*64 + (i>>6)]; }
    if (i < 1024){ w3T[i] = w3[(i&15)*64 + (i>>4)]; }
    if (i < 3072){ const int k=i/48, r=i%48, q=r>>4, c=r&15; w1P[i] = w1[k*48 + 3*c + q]; }
    if (i < 1296){ const int t=i/48, r=i%48, q=r>>4, c=r&15; wpT[i] = wp[(3*c+q)*27 + t]; }
    if (i < 48)  { const int q=i>>4, c=i&15; bpP[i] = bp[3*c + q]; }
}

// global max of x0 ch3 -> slot (pre-max for step 0; initial mask is all-ones)
__global__ __launch_bounds__(256) void prep_kernel(const float* __restrict__ x3,
    float* __restrict__ maskA, unsigned* __restrict__ slot)
{
    const int idx = blockIdx.x*256 + threadIdx.x;
    maskA[idx] = 1.0f;
    float v = x3[idx];
    #pragma unroll
    for (int o=32;o;o>>=1) v = fmaxf(v, __shfl_down(v, o));
    __shared__ float red[4];
    const int lane = threadIdx.x & 63, wid = threadIdx.x >> 6;
    if (lane==0) red[wid]=v;
    __syncthreads();
    if (threadIdx.x==0){
        float m = fmaxf(fmaxf(red[0],red[1]), fmaxf(red[2],red[3]));
        atomicMax(slot, encf(m));
    }
}

struct XBuf { float x[16]; float m; int v; };

__device__ __forceinline__ void prefetch_t(int t, int d, int h, int w,
    const float* __restrict__ xin, const float* __restrict__ min_, XBuf& B)
{
    const int zz = d + t/9 - 1;
    const int yy = h + (t/3)%3 - 1;
    const int xx = w + t%3 - 1;
    const int zc = clampi(zz), yc = clampi(yy), xc = clampi(xx);
    B.v = (zz==zc) & (yy==yc) & (xx==xc);
    const int noff = zc*DSTRIDE + yc*Dn + xc;
    B.m = min_[noff];
    #pragma unroll
    for (int c=0;c<16;++c) B.x[c] = xin[(size_t)c*Sn + noff];
}

__device__ __forceinline__ void accum_t(int t, const XBuf& A,
    const float* __restrict__ wpT, v2f* pv)
{
    const float mv = A.v ? A.m : 0.0f;
    const v2f mvv = {mv, mv};
    const float* wrow = wpT + t*48;
    #pragma unroll
    for (int i=0;i<8;++i){
        v2f xv = {A.x[2*i], A.x[2*i+1]};
        v2f xm = xv * mvv;                               // v_pk_mul_f32
        pv[i]    = __builtin_elementwise_fma(ld2(wrow + 2*i),      xm, pv[i]);
        pv[8+i]  = __builtin_elementwise_fma(ld2(wrow + 16 + 2*i), xm, pv[8+i]);
        pv[16+i] = __builtin_elementwise_fma(ld2(wrow + 32 + 2*i), xm, pv[16+i]);
    }
}

// fused: masked stencil dwconv -> MLP 48->64->64->16 (packed f32, k-outer pw1+pw2)
// -> residual -> unmasked x_new; atomicMax of new ch3 -> slot_post
__global__ __launch_bounds__(256, 2) void update_kernel(
    const float* __restrict__ xin, const float* __restrict__ min_,
    float* __restrict__ xout,
    const float* __restrict__ wpT, const float* __restrict__ bpP,
    const float* __restrict__ w1P, const float* __restrict__ b1,
    const float* __restrict__ w2T, const float* __restrict__ b2,
    const float* __restrict__ w3T, const float* __restrict__ b3,
    unsigned* __restrict__ slot_post)
{
    const int tid = threadIdx.x;
    const int w = blockIdx.x*32 + (tid & 31);
    const int h = blockIdx.y*8  + (tid >> 5);
    const int d = blockIdx.z;
    const int idx = d*DSTRIDE + h*Dn + w;

    // p in o' = q*16+c layout, packed pairs (c even, c odd)
    v2f pv[24];
    #pragma unroll
    for (int j=0;j<24;++j) pv[j] = ld2(bpP + 2*j);

    // software-pipelined stencil: prefetch t+1 while computing t
    XBuf A, B;
    prefetch_t(0, d, h, w, xin, min_, A);
    #pragma unroll 1
    for (int t=0; t<26; t+=2){
        prefetch_t(t+1, d, h, w, xin, min_, B);
        accum_t(t, A, wpT, pv);
        prefetch_t(t+2, d, h, w, xin, min_, A);
        accum_t(t+1, B, wpT, pv);
    }
    accum_t(26, A, wpT, pv);

    // k-outer fused pw1+pw2 (packed): h1k on the fly, rank-1 update of acc2
    v2f acc2v[32];
    #pragma unroll
    for (int j=0;j<32;++j) acc2v[j] = ld2(b2 + 2*j);

    #pragma unroll 1
    for (int k=0;k<64;++k){
        const float* w1row = w1P + k*48;
        v2f av0 = {b1[k], 0.0f};
        v2f av1 = {0.0f, 0.0f};
        #pragma unroll
        for (int i=0;i<12;++i){
            av0 = __builtin_elementwise_fma(ld2(w1row + 4*i),     pv[2*i],   av0);
            av1 = __builtin_elementwise_fma(ld2(w1row + 4*i + 2), pv[2*i+1], av1);
        }
        const float a = (av0.x + av1.x) + (av0.y + av1.y);
        const float h1k = ftanh(a);
        const v2f hv = {h1k, h1k};
        const float* w2row = w2T + k*64;
        #pragma unroll
        for (int j=0;j<32;++j)
            acc2v[j] = __builtin_elementwise_fma(ld2(w2row + 2*j), hv, acc2v[j]);
    }

    // pw3 (packed, fully unrolled: const-indexed acc2v)
    v2f oaccv[8];
    #pragma unroll
    for (int c=0;c<8;++c) oaccv[c] = ld2(b3 + 2*c);

    #pragma unroll
    for (int jp=0;jp<32;++jp){
        const float h2a = ftanh(acc2v[jp].x);
        const float h2b = ftanh(acc2v[jp].y);
        const v2f ha = {h2a, h2a}, hb = {h2b, h2b};
        const float* r0 = w3T + (2*jp)*16;
        const float* r1 = w3T + (2*jp+1)*16;
        #pragma unroll
        for (int c=0;c<8;++c){
            oaccv[c] = __builtin_elementwise_fma(ld2(r0 + 2*c), ha, oaccv[c]);
            oaccv[c] = __builtin_elementwise_fma(ld2(r1 + 2*c), hb, oaccv[c]);
        }
    }

    // residual: x_new = masked x_in + out; track ch3 for global max
    const float mcen = min_[idx];
    float v3 = 0.0f;
    #pragma unroll
    for (int c=0;c<16;++c){
        const float oc = (c & 1) ? oaccv[c>>1].y : oaccv[c>>1].x;
        const float xn = fmaf(xin[(size_t)c*Sn+idx], mcen, oc);
        xout[(size_t)c*Sn+idx] = xn;
        if (c==3) v3 = xn;
    }

    #pragma unroll
    for (int o=32;o;o>>=1) v3 = fmaxf(v3, __shfl_down(v3, o));
    if ((tid & 63) == 0) atomicMax(slot_post, encf(v3));
}

// alive0 from masked old ch3, alive1 from unmasked new ch3; life mask includes
// the boundary zero x[:, :, -1, 48:, :]=0; also produces next step's pre-max
__global__ __launch_bounds__(256) void mask_kernel(
    const float* __restrict__ xin3, const float* __restrict__ min_,
    const float* __restrict__ xout3, float* __restrict__ mout,
    const unsigned* __restrict__ slot_pre, const unsigned* __restrict__ slot_post,
    unsigned* __restrict__ slot_next)
{
    const int idx = blockIdx.x*256 + threadIdx.x;
    const int w = idx % Dn;
    const int h = (idx / Dn) % Dn;
    const int d = idx / DSTRIDE;
    const float th0 = 0.1f * decf(*slot_pre);
    const float th1 = 0.1f * decf(*slot_post);
    float a0 = -INFINITY, a1 = -INFINITY;
    #pragma unroll
    for (int t=0;t<27;++t){
        const int dz=t/9-1, dy=(t/3)%3-1, dx=t%3-1;
        const int zz=d+dz, yy=h+dy, xx=w+dx;
        if ((unsigned)zz<(unsigned)Dn && (unsigned)yy<(unsigned)Dn &&
            (unsigned)xx<(unsigned)Dn){
            const int noff = idx + dz*DSTRIDE + dy*Dn + dx;
            a0 = fmaxf(a0, xin3[noff]*min_[noff]);
            a1 = fmaxf(a1, xout3[noff]);
        }
    }
    const bool life = (a0 > th0) && (a1 > th1) && !(d==Dn-1 && h>=48);
    const float mv = life ? 1.0f : 0.0f;
    mout[idx] = mv;

    float f3 = xout3[idx]*mv;   // final ch3 value -> pre-max of next step
    #pragma unroll
    for (int o=32;o;o>>=1) f3 = fmaxf(f3, __shfl_down(f3, o));
    __shared__ float red[4];
    const int lane = threadIdx.x & 63, wid = threadIdx.x >> 6;
    if (lane==0) red[wid]=f3;
    __syncthreads();
    if (threadIdx.x==0){
        float m = fmaxf(fmaxf(red[0],red[1]), fmaxf(red[2],red[3]));
        atomicMax(slot_next, encf(m));
    }
}

// final: apply last step's mask in place on d_out
__global__ __launch_bounds__(256) void apply_kernel(float* __restrict__ x,
    const float* __restrict__ mk)
{
    const int idx = blockIdx.x*256 + threadIdx.x;
    const float m = mk[idx];
    #pragma unroll
    for (int c=0;c<Cn;++c) x[(size_t)c*Sn+idx] *= m;
}

extern "C" void kernel_launch(void* const* d_in, const int* in_sizes, int n_in,
                              void* d_out, int out_size, void* d_ws, size_t ws_size,
                              hipStream_t stream)
{
    const float* x0 = (const float*)d_in[0];
    const float* wp = (const float*)d_in[1];
    const float* bp = (const float*)d_in[2];
    const float* w1 = (const float*)d_in[3];
    const float* b1 = (const float*)d_in[4];
    const float* w2 = (const float*)d_in[5];
    const float* b2 = (const float*)d_in[6];
    const float* w3 = (const float*)d_in[7];
    const float* b3 = (const float*)d_in[8];
    float* out = (float*)d_out;

    // ws: xbuf 16*Sn | maskA Sn | maskB Sn | maxv 16 u32 | w2T 4096 | w3T 1024 |
    //     w1P 3072 | wpT 1296 | bpP 48   (~63.75 MB)
    float* xbuf  = (float*)d_ws;
    float* maskA = xbuf + (size_t)Cn*Sn;
    float* maskB = maskA + Sn;
    unsigned* maxv = (unsigned*)(maskB + Sn);
    float* w2T = (float*)(maxv + 16);
    float* w3T = w2T + 4096;
    float* w1P = w3T + 1024;
    float* wpT = w1P + 3072;
    float* bpP = wpT + 1296;

    init_kernel<<<1, 64, 0, stream>>>(maxv);
    tr_kernel<<<16, 256, 0, stream>>>(w2, w3, w1, wp, bp, w2T, w3T, w1P, wpT, bpP);
    prep_kernel<<<Sn/256, 256, 0, stream>>>(x0 + (size_t)3*Sn, maskA, &maxv[0]);

    // ping-pong unmasked x_new between ws buffer and d_out; masks alternate A/B
    const float* xi[4] = {x0,   xbuf, out,  xbuf};
    float*       xo[4] = {xbuf, out,  xbuf, out};
    const float* mi[4] = {maskA, maskB, maskA, maskB};
    float*       mo[4] = {maskB, maskA, maskB, maskA};

    dim3 ugrid(Dn/32, Dn/8, Dn);
    for (int s=0; s<4; ++s){
        update_kernel<<<ugrid, 256, 0, stream>>>(xi[s], mi[s], xo[s],
            wpT, bpP, w1P, b1, w2T, b2, w3T, b3, &maxv[2*s+1]);
        mask_kernel<<<Sn/256, 256, 0, stream>>>(xi[s]+(size_t)3*Sn, mi[s],
            xo[s]+(size_t)3*Sn, mo[s], &maxv[2*s], &maxv[2*s+1], &maxv[2*s+2]);
    }
    apply_kernel<<<Sn/256, 256, 0, stream>>>(out, maskA);
}